// Round 6
// baseline (164.253 us; speedup 1.0000x reference)
//
#include <hip/hip_runtime.h>

// NCC2D fused single-kernel: DMA staging (R4 core) + SINGLE 9-row LDS buffer.
// R4 post-mortem: double buffer (75 KB) -> 1 block/CU, Occ 11%, nothing hid
// the DMA drain. R5 post-mortem: VGPR staging (stg[9] via lambdas) -> ring
// spilled, 89 MB scratch writes. Resolution: keep global_load_lds (zero
// staging VGPRs, R4 allocated cleanly at 88 VGPR) and shrink LDS to one
// 9-row buffer (18 x 520 x 4 = 37.5 KB -> 4 blocks/CU). Overlap comes from
// cross-block co-residency, not intra-block double-buffering.
// SH=19 -> 27 strips x 32 images = 864 blocks (~3.4/CU). Rounds of NINE so
// the vertical ring slot is the literal inner-loop index (static; dynamic
// index -> scratch, R3 lesson). No lambdas touching register arrays.
// Finish: block reduce -> device atomicAdd + completion counter in d_ws
// (zeroed by hipMemsetAsync); last block writes -mean.

#define BATCH   32
#define IMH     512
#define IMW     512
#define SH      19          // output rows per block
#define NSTRIP  27          // 27*19 = 513 >= 512 (tail masked)
#define NROUND  3           // 27 input rows = 3 rounds x 9
#define NBLOCKS (BATCH * NSTRIP)
#define LROW    520         // [0..4)=0, [4..516)=data, [516..520)=0
#define AROWS   18          // 2 arr x 9 rows (single buffer)
#define LDSZ    (AROWS * LROW)

__global__ __launch_bounds__(256, 4) void ncc_main(const float* __restrict__ I,
                                                   const float* __restrict__ J,
                                                   float* __restrict__ acc_ws,
                                                   unsigned* __restrict__ cnt_ws,
                                                   float* __restrict__ out) {
    __shared__ __align__(16) float lds[LDSZ];
    __shared__ float wsum[4];

    const int t    = threadIdx.x;
    const int lane = t & 63;
    const int w    = t >> 6;     // wave 0..3
    const int arr  = w >> 1;     // 0: stage I rows, 1: stage J rows
    const int h    = w & 1;      // half-row (256 floats)
    const int s    = blockIdx.x; // strip
    const int b    = blockIdx.y; // image
    const int r0   = s * SH;
    const float inv81 = 1.0f / 81.0f;

    const float* Ib  = I + (size_t)b * IMH * IMW;
    const float* Jb  = J + (size_t)b * IMH * IMW;
    const float* src = arr ? Jb : Ib;
    float* const abase = &lds[arr * 9 * LROW];   // this wave's array block

    // ---- DMA round 0 (9 rows, one global_load_lds dwordx4 per row) ----
#pragma unroll
    for (int q = 0; q < 9; ++q) {
        const int ri = r0 - 4 + q;
        float* ldst = abase + q * LROW + 4 + h * 256;
        if ((unsigned)ri < (unsigned)IMH) {
            const float* gsrc = src + (size_t)ri * IMW + h * 256 + lane * 4;
            __builtin_amdgcn_global_load_lds(
                (const __attribute__((address_space(1))) void*)gsrc,
                (__attribute__((address_space(3))) void*)ldst, 16, 0, 0);
        } else {
            *(float4*)(ldst + lane * 4) = make_float4(0.f, 0.f, 0.f, 0.f);
        }
    }

    // zero the +-4 pads of all 18 LDS rows (once; DMA never touches pads)
    if (t < AROWS * 8) {
        const int arow = t >> 3;
        const int k    = t & 7;
        lds[arow * LROW + ((k < 4) ? k : (512 + k))] = 0.f;
    }
    __syncthreads();   // drains DMA(0) + pad writes

    // ring[j][q]: horizontal sums H of the last 9 input rows
    // q: 0=I 1=J 2=II 3=JJ 4=IJ ; .x = col 2t, .y = col 2t+1
    float2 ring[9][5];
#pragma unroll
    for (int j = 0; j < 9; ++j)
#pragma unroll
        for (int q = 0; q < 5; ++q) ring[j][q] = make_float2(0.f, 0.f);

    float2 V[5];
#pragma unroll
    for (int q = 0; q < 5; ++q) V[q] = make_float2(0.f, 0.f);

    float2 acc = make_float2(0.f, 0.f);

    const int baseI = 2 * t;              // pads make word 2t == col 2t-4
    const int baseJ = 9 * LROW + 2 * t;

#pragma unroll 1
    for (int R = 0; R < NROUND; ++R) {
#pragma unroll
        for (int j = 0; j < 9; ++j) {      // j IS the ring slot (static)
            const int i = R * 9 + j;       // row iteration 0..26

            float vI[10], vJ[10];
#pragma unroll
            for (int k = 0; k < 5; ++k) {
                const float2 a = *(const float2*)&lds[baseI + j * LROW + 2 * k];
                const float2 c = *(const float2*)&lds[baseJ + j * LROW + 2 * k];
                vI[2 * k] = a.x; vI[2 * k + 1] = a.y;
                vJ[2 * k] = c.x; vJ[2 * k + 1] = c.y;
            }

            float sI = 0.f, sJ = 0.f, sII = 0.f, sJJ = 0.f, sIJ = 0.f;
#pragma unroll
            for (int m = 0; m < 9; ++m) {
                sI  += vI[m];
                sJ  += vJ[m];
                sII += vI[m] * vI[m];
                sJJ += vJ[m] * vJ[m];
                sIJ += vI[m] * vJ[m];
            }
            const float i0 = vI[0], j0 = vJ[0], i9 = vI[9], j9 = vJ[9];
            float2 Hn[5];
            Hn[0] = make_float2(sI,  sI  + i9      - i0);
            Hn[1] = make_float2(sJ,  sJ  + j9      - j0);
            Hn[2] = make_float2(sII, sII + i9 * i9 - i0 * i0);
            Hn[3] = make_float2(sJJ, sJJ + j9 * j9 - j0 * j0);
            Hn[4] = make_float2(sIJ, sIJ + i9 * j9 - i0 * j0);

#pragma unroll
            for (int q = 0; q < 5; ++q) {
                const float2 old = ring[j][q];
                ring[j][q] = Hn[q];
                V[q].x += Hn[q].x - old.x;
                V[q].y += Hn[q].y - old.y;
            }

            if (i >= 8 && (r0 + i - 8) < IMH) {
                {
                    const float aI = V[0].x, aJ = V[1].x;
                    const float cross = V[4].x - aI * aJ * inv81;
                    const float iv    = V[2].x - aI * aI * inv81;
                    const float jv    = V[3].x - aJ * aJ * inv81;
                    acc.x += cross * cross *
                             __builtin_amdgcn_rcpf(iv * jv + 1e-5f);
                }
                {
                    const float aI = V[0].y, aJ = V[1].y;
                    const float cross = V[4].y - aI * aJ * inv81;
                    const float iv    = V[2].y - aI * aI * inv81;
                    const float jv    = V[3].y - aJ * aJ * inv81;
                    acc.y += cross * cross *
                             __builtin_amdgcn_rcpf(iv * jv + 1e-5f);
                }
            }
        }

        if (R + 1 < NROUND) {
            __syncthreads();   // all reads of round R done (single buffer)
            // ---- DMA round R+1 into the same buffer ----
#pragma unroll
            for (int q = 0; q < 9; ++q) {
                const int ri = r0 - 4 + (R + 1) * 9 + q;
                float* ldst = abase + q * LROW + 4 + h * 256;
                if ((unsigned)ri < (unsigned)IMH) {
                    const float* gsrc = src + (size_t)ri * IMW + h * 256 + lane * 4;
                    __builtin_amdgcn_global_load_lds(
                        (const __attribute__((address_space(1))) void*)gsrc,
                        (__attribute__((address_space(3))) void*)ldst, 16, 0, 0);
                } else {
                    *(float4*)(ldst + lane * 4) = make_float4(0.f, 0.f, 0.f, 0.f);
                }
            }
            __syncthreads();   // drains DMA; data visible to all waves
        }
    }

    // block reduction: wave shuffle, then LDS across the 4 waves
    float sum = acc.x + acc.y;
#pragma unroll
    for (int off = 32; off > 0; off >>= 1) sum += __shfl_down(sum, off, 64);

    if ((t & 63) == 0) wsum[t >> 6] = sum;
    __syncthreads();
    if (t == 0) {
        const float bsum = wsum[0] + wsum[1] + wsum[2] + wsum[3];
        atomicAdd(acc_ws, bsum);          // device-scope
        __threadfence();
        const unsigned old = atomicAdd(cnt_ws, 1u);
        if (old == (unsigned)(NBLOCKS - 1)) {
            const float total = atomicAdd(acc_ws, 0.0f);  // coherent read
            out[0] = -total / 8388608.0f;                 // -mean over 32*512*512
        }
    }
}

extern "C" void kernel_launch(void* const* d_in, const int* in_sizes, int n_in,
                              void* d_out, int out_size, void* d_ws, size_t ws_size,
                              hipStream_t stream) {
    const float* I = (const float*)d_in[0];  // y_true
    const float* J = (const float*)d_in[1];  // y_pred
    float* acc_ws  = (float*)d_ws;           // ws[0]: running sum
    unsigned* cnt  = (unsigned*)d_ws + 1;    // ws[1]: completion counter
    float* out     = (float*)d_out;

    hipMemsetAsync(d_ws, 0, 2 * sizeof(float), stream);

    dim3 grid(NSTRIP, BATCH);
    ncc_main<<<grid, 256, 0, stream>>>(I, J, acc_ws, cnt, out);
}